// Round 8
// baseline (1155.906 us; speedup 1.0000x reference)
//
#include <hip/hip_runtime.h>

// ---------------------------------------------------------------------------
// PIDMultiHeadAttention — Round 8.
// Every LDS-staged GEMM variant plateaued (R4 293us lane-writes+conflicts,
// R6 723us DMA serialization, R7 373us clean-copy+conflicts) — the K-loop's
// load->vmcnt->ds_write->barrier->ds_read chain is latency-bound at 3
// blocks/CU with no more TLP available. This round: LDS-FREE direct-fragment
// GEMM. The MFMA fragment [row=lane&15][k=quad*8..+8] is a 16B/lane load
// straight from the row-major matrix; consecutive k-steps reuse the same
// 128B line (L2-served). Barrier-free k-loop -> compiler pipelines freely.
//  * wave = independent 64x64 tile, block = 2x2 waves (128x128), no LDS
//  * g-scale fold at seg boundaries (proven R6/R7); seg2 = VALU frag diff
//  * attention / scans / gates unchanged (isolate the variable)
// ---------------------------------------------------------------------------

#define D_MODEL 1024
#define T_SEQ   2048
#define B_SZ    2
#define M_ROWS  (B_SZ * T_SEQ)   // 4096
#define N_HEADS 16
#define D_HEAD  64

typedef unsigned short u16;
typedef unsigned int   u32;

typedef short  short8  __attribute__((ext_vector_type(8)));
typedef float  float4v __attribute__((ext_vector_type(4)));

__device__ __forceinline__ float bf2f(u16 u) {
    union { u32 i; float f; } c; c.i = ((u32)u) << 16; return c.f;
}
__device__ __forceinline__ u16 f2bf(float f) {
    union { float f; u32 i; } c; c.f = f;
    u32 i = c.i;
    i += 0x7FFFu + ((i >> 16) & 1u);   // RNE
    return (u16)(i >> 16);
}
__device__ __forceinline__ float ldin(const void* p, int i, int fl) {
    return fl ? ((const float*)p)[i] : bf2f(((const u16*)p)[i]);
}

// ---------------------------------------------------------------------------
// 0) wire-dtype detection (unchanged — passing since round 2)
// ---------------------------------------------------------------------------
__global__ void detect_kernel(const u32* __restrict__ x, int* __restrict__ flag)
{
    if (threadIdx.x == 0 && blockIdx.x == 0) {
        int good = 0;
        for (int i = 0; i < 256; ++i) {
            union { u32 u; float f; } c; c.u = x[i];
            float a = fabsf(c.f);
            if (c.f == c.f && a > 1e-8f && a < 1e4f) ++good;
        }
        *flag = (good >= 192) ? 1 : 0;
    }
}

// ---------------------------------------------------------------------------
// 1) cumulative-mean scan (unchanged)
// ---------------------------------------------------------------------------
__global__ __launch_bounds__(256) void scan_partial(
    const void* __restrict__ x, float* __restrict__ csum,
    const int* __restrict__ flagp)
{
    int fl = *flagp;
    int tid = blockIdx.x * 256 + threadIdx.x;   // 32768 = B * 16 * D
    int b = tid >> 14;
    int c = (tid >> 10) & 15;
    int d = tid & 1023;
    int base = (b * T_SEQ + c * 128) * D_MODEL + d;
    float s = 0.f;
#pragma unroll 8
    for (int t = 0; t < 128; ++t) s += ldin(x, base + t * D_MODEL, fl);
    csum[tid] = s;
}

__global__ __launch_bounds__(256) void scan_final(
    const void* __restrict__ x, const float* __restrict__ csum,
    u16* __restrict__ integ, const int* __restrict__ flagp)
{
    int fl = *flagp;
    int tid = blockIdx.x * 256 + threadIdx.x;
    int b = tid >> 14;
    int c = (tid >> 10) & 15;
    int d = tid & 1023;
    float pre = 0.f;
    int cbase = (b << 14) | d;
    for (int cc = 0; cc < c; ++cc) pre += csum[cbase + (cc << 10)];
    int base = (b * T_SEQ + c * 128) * D_MODEL + d;
    float run = pre;
    int t0 = c * 128;
    for (int t = 0; t < 128; ++t) {
        run += ldin(x, base + t * D_MODEL, fl);
        integ[base + t * D_MODEL] = f2bf(run / (float)(t0 + t + 1));
    }
}

// ---------------------------------------------------------------------------
// 2) gate softmax (unchanged)
// ---------------------------------------------------------------------------
__global__ __launch_bounds__(64) void gates_kernel(
    const void* __restrict__ x,
    const void* __restrict__ qWg, const void* __restrict__ qbg,
    const void* __restrict__ kWg, const void* __restrict__ kbg,
    const void* __restrict__ vWg, const void* __restrict__ vbg,
    float* __restrict__ gq, float* __restrict__ gk, float* __restrict__ gv,
    const int* __restrict__ flagp)
{
    int fl = *flagp;
    int row = blockIdx.x;
    int l = threadIdx.x;
    int xb = row * D_MODEL;
    float p[9];
#pragma unroll
    for (int j = 0; j < 9; ++j) p[j] = 0.f;
#pragma unroll 4
    for (int i = 0; i < 16; ++i) {
        int d = l + 64 * i;
        float xv = ldin(x, xb + d, fl);
        p[0] += xv * ldin(qWg, d, fl);
        p[1] += xv * ldin(qWg, 1024 + d, fl);
        p[2] += xv * ldin(qWg, 2048 + d, fl);
        p[3] += xv * ldin(kWg, d, fl);
        p[4] += xv * ldin(kWg, 1024 + d, fl);
        p[5] += xv * ldin(kWg, 2048 + d, fl);
        p[6] += xv * ldin(vWg, d, fl);
        p[7] += xv * ldin(vWg, 1024 + d, fl);
        p[8] += xv * ldin(vWg, 2048 + d, fl);
    }
#pragma unroll
    for (int off = 32; off > 0; off >>= 1) {
#pragma unroll
        for (int j = 0; j < 9; ++j) p[j] += __shfl_down(p[j], off);
    }
    if (l == 0) {
        const void* bgs[3] = { qbg, kbg, vbg };
        float* outs[3] = { gq, gk, gv };
#pragma unroll
        for (int pr = 0; pr < 3; ++pr) {
            float a0 = p[pr * 3 + 0] + ldin(bgs[pr], 0, fl);
            float a1 = p[pr * 3 + 1] + ldin(bgs[pr], 1, fl);
            float a2 = p[pr * 3 + 2] + ldin(bgs[pr], 2, fl);
            float mx = fmaxf(a0, fmaxf(a1, a2));
            float e0 = __expf(a0 - mx), e1 = __expf(a1 - mx), e2 = __expf(a2 - mx);
            float inv = 1.f / (e0 + e1 + e2);
            outs[pr][row * 3 + 0] = e0 * inv;
            outs[pr][row * 3 + 1] = e1 * inv;
            outs[pr][row * 3 + 2] = e2 * inv;
        }
    }
}

// ---------------------------------------------------------------------------
// 3) LDS-free direct-fragment MFMA GEMM.
//    Wave = independent 64x64 (m x n) output tile; block = 2x2 waves.
//    Fragment load: af[ms][lane] = A[(m0+ms*16+(l&15))*1024 + k0 + (l>>4)*8]
//    (16B/lane, same verified layout the LDS version read). No LDS, no
//    __syncthreads in the k-loop.
//    MODE 0: PID proj — segs {x, runmean, diff(x)} x {Wp,Wi,Wd}, g-fold at
//            seg end, head-major bf16 output.
//    MODE 1: out proj — K=1024, +bias, wire-dtype store.
// ---------------------------------------------------------------------------
struct GemmArgs {
    const void* W[3][3];
    const float* G[3];
    u16* C[3];
};

template<int MODE>
__global__ __launch_bounds__(256, 2) void mfma_gemm(
    const void* __restrict__ X, const u16* __restrict__ Ib,
    const u16* __restrict__ Abf, GemmArgs args,
    const void* __restrict__ bias, void* __restrict__ outp,
    const int* __restrict__ flagp)
{
    int fl = *flagp;
    int tid = threadIdx.x;
    int l = tid & 63, w = tid >> 6;
    int wm = w >> 1, wn = w & 1;
    int m0 = blockIdx.y * 128 + wm * 64;
    int n0 = blockIdx.x * 128 + wn * 64;
    int z = blockIdx.z;
    int lane15 = l & 15, quad = l >> 4;
    int kq = quad * 8;

    const float* G = nullptr;
    u16* Chead = nullptr;
    const void* Wseg[3];
    if (MODE == 0) {
        Wseg[0] = args.W[z][0]; Wseg[1] = args.W[z][1]; Wseg[2] = args.W[z][2];
        G = args.G[z]; Chead = args.C[z];
    } else {
        Wseg[0] = args.W[0][0]; Wseg[1] = Wseg[0]; Wseg[2] = Wseg[0];
    }

    int arow[4], nrow[4];
#pragma unroll
    for (int i = 0; i < 4; ++i) {
        arow[i] = m0 + i * 16 + lane15;
        nrow[i] = n0 + i * 16 + lane15;
    }
    bool t0r[4];
    int prow[4];
#pragma unroll
    for (int i = 0; i < 4; ++i) {
        t0r[i] = ((arow[i] & (T_SEQ - 1)) == 0);
        prow[i] = t0r[i] ? arow[i] : arow[i] - 1;   // clamped (masked to 0 later)
    }

    // bf16 fragment load straight from global
    auto ldfrag = [&](const u16* p, int row, int kk) -> short8 {
        return *(const short8*)(p + row * 1024 + kk);
    };
    // fp32-wire fragment load + convert (insurance path)
    auto ldfragf = [&](const float* p, int row, int kk) -> short8 {
        float4 a = *(const float4*)(p + row * 1024 + kk);
        float4 b = *(const float4*)(p + row * 1024 + kk + 4);
        short8 o;
        o[0]=(short)f2bf(a.x); o[1]=(short)f2bf(a.y);
        o[2]=(short)f2bf(a.z); o[3]=(short)f2bf(a.w);
        o[4]=(short)f2bf(b.x); o[5]=(short)f2bf(b.y);
        o[6]=(short)f2bf(b.z); o[7]=(short)f2bf(b.w);
        return o;
    };

    float4v accs[4][4], acct[4][4];
#pragma unroll
    for (int i = 0; i < 4; ++i)
#pragma unroll
        for (int j = 0; j < 4; ++j)
#pragma unroll
            for (int r = 0; r < 4; ++r) { accs[i][j][r] = 0.f; acct[i][j][r] = 0.f; }

    const int NSEG = (MODE == 0) ? 3 : 1;
    for (int seg = 0; seg < NSEG; ++seg) {
        const u16* Wp16 = (const u16*)Wseg[seg];
        const float* Wp32 = (const float*)Wseg[seg];
#pragma unroll 2
        for (int k0 = 0; k0 < 1024; k0 += 32) {
            int kk = k0 + kq;
            short8 af[4], bf[4];
            // ---- A fragments ----
            if (MODE == 1) {
#pragma unroll
                for (int ms = 0; ms < 4; ++ms) af[ms] = ldfrag(Abf, arow[ms], kk);
            } else if (seg == 1) {
#pragma unroll
                for (int ms = 0; ms < 4; ++ms) af[ms] = ldfrag(Ib, arow[ms], kk);
            } else if (seg == 0) {
                if (!fl) {
#pragma unroll
                    for (int ms = 0; ms < 4; ++ms)
                        af[ms] = ldfrag((const u16*)X, arow[ms], kk);
                } else {
#pragma unroll
                    for (int ms = 0; ms < 4; ++ms)
                        af[ms] = ldfragf((const float*)X, arow[ms], kk);
                }
            } else {   // seg == 2: derivative, per-lane diff
#pragma unroll
                for (int ms = 0; ms < 4; ++ms) {
                    if (!fl) {
                        short8 c8 = ldfrag((const u16*)X, arow[ms], kk);
                        short8 p8 = ldfrag((const u16*)X, prow[ms], kk);
                        short8 d8;
#pragma unroll
                        for (int j = 0; j < 8; ++j) {
                            float dv = bf2f((u16)c8[j]) - bf2f((u16)p8[j]);
                            d8[j] = t0r[ms] ? (short)0 : (short)f2bf(dv);
                        }
                        af[ms] = d8;
                    } else {
                        const float* xp = (const float*)X;
                        float4 c0 = *(const float4*)(xp + arow[ms] * 1024 + kk);
                        float4 c1 = *(const float4*)(xp + arow[ms] * 1024 + kk + 4);
                        float4 q0 = *(const float4*)(xp + prow[ms] * 1024 + kk);
                        float4 q1 = *(const float4*)(xp + prow[ms] * 1024 + kk + 4);
                        float v[8] = { c0.x-q0.x, c0.y-q0.y, c0.z-q0.z, c0.w-q0.w,
                                       c1.x-q1.x, c1.y-q1.y, c1.z-q1.z, c1.w-q1.w };
                        short8 d8;
#pragma unroll
                        for (int j = 0; j < 8; ++j)
                            d8[j] = t0r[ms] ? (short)0 : (short)f2bf(v[j]);
                        af[ms] = d8;
                    }
                }
            }
            // ---- B fragments ----
            if (!fl) {
#pragma unroll
                for (int ns = 0; ns < 4; ++ns) bf[ns] = ldfrag(Wp16, nrow[ns], kk);
            } else {
#pragma unroll
                for (int ns = 0; ns < 4; ++ns) bf[ns] = ldfragf(Wp32, nrow[ns], kk);
            }
            // ---- 16 MFMAs ----
#pragma unroll
            for (int ms = 0; ms < 4; ++ms)
#pragma unroll
                for (int ns = 0; ns < 4; ++ns)
                    accs[ms][ns] = __builtin_amdgcn_mfma_f32_16x16x32_bf16(
                        af[ms], bf[ns], accs[ms][ns], 0, 0, 0);
        }
        // ---- fold seg-partial into total with per-row g ----
        if (MODE == 0) {
#pragma unroll
            for (int ms = 0; ms < 4; ++ms) {
#pragma unroll
                for (int r = 0; r < 4; ++r) {
                    int m = m0 + ms * 16 + quad * 4 + r;
                    float gv = G[m * 3 + seg];
#pragma unroll
                    for (int ns = 0; ns < 4; ++ns) {
                        acct[ms][ns][r] += gv * accs[ms][ns][r];
                        accs[ms][ns][r] = 0.f;
                    }
                }
            }
        }
    }

    // ---- epilogue (same math as rounds 6/7 — proven) ----
#pragma unroll
    for (int ms = 0; ms < 4; ++ms) {
#pragma unroll
        for (int r = 0; r < 4; ++r) {
            int m = m0 + ms * 16 + quad * 4 + r;
#pragma unroll
            for (int ns = 0; ns < 4; ++ns) {
                int n = n0 + ns * 16 + lane15;
                if (MODE == 0) {
                    float vv = acct[ms][ns][r];
                    int b = m >> 11, t = m & (T_SEQ - 1);
                    int h = n >> 6,  d = n & 63;
                    Chead[(((b << 4) + h) * T_SEQ + t) * 64 + d] = f2bf(vv);
                } else {
                    float vv = accs[ms][ns][r] + ldin(bias, n, fl);
                    if (fl) ((float*)outp)[m * 1024 + n] = vv;
                    else    ((u16*)outp)[m * 1024 + n] = f2bf(vv);
                }
            }
        }
    }
}

// ---------------------------------------------------------------------------
// 4) MFMA flash attention (unchanged — passing since round 3)
// ---------------------------------------------------------------------------
__global__ __launch_bounds__(256) void attn_mfma(
    const u16* __restrict__ Qh, const u16* __restrict__ Kh,
    const u16* __restrict__ Vh, u16* __restrict__ AO)
{
    int bx = blockIdx.x;          // 1024 = B*H*(T/64)
    int qt = bx & 31;
    int bh = bx >> 5;             // 0..31
    int h  = bh & 15;
    int b  = bh >> 4;
    int tid = threadIdx.x;
    int l   = tid & 63;
    int w   = tid >> 6;
    int lane15 = l & 15;
    int quad   = l >> 4;

    __shared__ __align__(16) u16 Ks[64 * 72];
    __shared__ __align__(16) u16 Vt[64 * 72];   // transposed: [d][t_local]
    __shared__ __align__(16) u16 Ps[4 * 16 * 72];

    const u16* Qb = Qh + bh * (T_SEQ * 64);
    const u16* Kb = Kh + bh * (T_SEQ * 64);
    const u16* Vb = Vh + bh * (T_SEQ * 64);

    int qrow = qt * 64 + w * 16 + lane15;
    short8 qf[2];
#pragma unroll
    for (int ks = 0; ks < 2; ++ks)
        qf[ks] = *(const short8*)&Qb[qrow * 64 + ks * 32 + quad * 8];

    float4v oacc[4];
#pragma unroll
    for (int ds = 0; ds < 4; ++ds)
#pragma unroll
        for (int r = 0; r < 4; ++r) oacc[ds][r] = 0.f;
    float mrun[4], lrun[4];
#pragma unroll
    for (int r = 0; r < 4; ++r) { mrun[r] = -1e30f; lrun[r] = 0.f; }

    int srow = tid >> 2;
    int sdc  = (tid & 3) * 16;

    for (int kt = 0; kt <= qt; ++kt) {
        {
            const u16* kp = &Kb[(kt * 64 + srow) * 64 + sdc];
            ushort4 a = *(const ushort4*)kp;
            ushort4 c = *(const ushort4*)(kp + 4);
            ushort4 d2 = *(const ushort4*)(kp + 8);
            ushort4 e = *(const ushort4*)(kp + 12);
            short8 p0, p1;
            p0[0]=a.x; p0[1]=a.y; p0[2]=a.z; p0[3]=a.w;
            p0[4]=c.x; p0[5]=c.y; p0[6]=c.z; p0[7]=c.w;
            p1[0]=d2.x; p1[1]=d2.y; p1[2]=d2.z; p1[3]=d2.w;
            p1[4]=e.x; p1[5]=e.y; p1[6]=e.z; p1[7]=e.w;
            *(short8*)&Ks[srow * 72 + sdc] = p0;
            *(short8*)&Ks[srow * 72 + sdc + 8] = p1;

            const u16* vp = &Vb[(kt * 64 + srow) * 64 + sdc];
            u16 vv[16];
            *(ushort4*)&vv[0]  = *(const ushort4*)vp;
            *(ushort4*)&vv[4]  = *(const ushort4*)(vp + 4);
            *(ushort4*)&vv[8]  = *(const ushort4*)(vp + 8);
            *(ushort4*)&vv[12] = *(const ushort4*)(vp + 12);
#pragma unroll
            for (int e2 = 0; e2 < 16; ++e2)
                Vt[(sdc + e2) * 72 + srow] = vv[e2];
        }
        __syncthreads();

        float4v sacc[4];
#pragma unroll
        for (int ns = 0; ns < 4; ++ns)
#pragma unroll
            for (int r = 0; r < 4; ++r) sacc[ns][r] = 0.f;
#pragma unroll
        for (int ks = 0; ks < 2; ++ks) {
#pragma unroll
            for (int ns = 0; ns < 4; ++ns) {
                short8 bfk = *(const short8*)&Ks[(ns * 16 + lane15) * 72 + ks * 32 + quad * 8];
                sacc[ns] = __builtin_amdgcn_mfma_f32_16x16x32_bf16(
                    qf[ks], bfk, sacc[ns], 0, 0, 0);
            }
        }

        int qg0 = qt * 64 + w * 16 + quad * 4;
#pragma unroll
        for (int ns = 0; ns < 4; ++ns) {
            int kg = kt * 64 + ns * 16 + lane15;
#pragma unroll
            for (int r = 0; r < 4; ++r) {
                float s = sacc[ns][r] * 0.125f;
                sacc[ns][r] = (kg > qg0 + r) ? -1e30f : s;
            }
        }
#pragma unroll
        for (int r = 0; r < 4; ++r) {
            float mx = fmaxf(fmaxf(sacc[0][r], sacc[1][r]),
                             fmaxf(sacc[2][r], sacc[3][r]));
#pragma unroll
            for (int m2 = 1; m2 < 16; m2 <<= 1)
                mx = fmaxf(mx, __shfl_xor(mx, m2, 64));
            float mnew = fmaxf(mrun[r], mx);
            float al = __expf(mrun[r] - mnew);
            float rs = 0.f;
#pragma unroll
            for (int ns = 0; ns < 4; ++ns) {
                float p = __expf(sacc[ns][r] - mnew);
                sacc[ns][r] = p;
                rs += p;
            }
#pragma unroll
            for (int m2 = 1; m2 < 16; m2 <<= 1)
                rs += __shfl_xor(rs, m2, 64);
            lrun[r] = lrun[r] * al + rs;
            mrun[r] = mnew;
#pragma unroll
            for (int ds = 0; ds < 4; ++ds) oacc[ds][r] *= al;
        }

        u16* Pw = &Ps[w * 16 * 72];
#pragma unroll
        for (int ns = 0; ns < 4; ++ns)
#pragma unroll
            for (int r = 0; r < 4; ++r)
                Pw[(quad * 4 + r) * 72 + ns * 16 + lane15] = f2bf(sacc[ns][r]);

#pragma unroll
        for (int ks = 0; ks < 2; ++ks) {
            short8 afp = *(const short8*)&Pw[lane15 * 72 + ks * 32 + quad * 8];
#pragma unroll
            for (int ds = 0; ds < 4; ++ds) {
                short8 bfv = *(const short8*)&Vt[(ds * 16 + lane15) * 72 + ks * 32 + quad * 8];
                oacc[ds] = __builtin_amdgcn_mfma_f32_16x16x32_bf16(
                    afp, bfv, oacc[ds], 0, 0, 0);
            }
        }
        __syncthreads();
    }

#pragma unroll
    for (int r = 0; r < 4; ++r) {
        float inv = 1.f / lrun[r];
        int t = qt * 64 + w * 16 + quad * 4 + r;
        int orow = (b * T_SEQ + t) * 1024 + h * 64;
#pragma unroll
        for (int ds = 0; ds < 4; ++ds)
            AO[orow + ds * 16 + lane15] = f2bf(oacc[ds][r] * inv);
    }
}

// ---------------------------------------------------------------------------
extern "C" void kernel_launch(void* const* d_in, const int* in_sizes, int n_in,
                              void* d_out, int out_size, void* d_ws, size_t ws_size,
                              hipStream_t stream)
{
    const void* x   = d_in[0];
    const void* qWp = d_in[1];
    const void* qWi = d_in[2];
    const void* qWd = d_in[3];
    const void* qWg = d_in[4];
    const void* qbg = d_in[5];
    const void* kWp = d_in[6];
    const void* kWi = d_in[7];
    const void* kWd = d_in[8];
    const void* kWg = d_in[9];
    const void* kbg = d_in[10];
    const void* vWp = d_in[11];
    const void* vWi = d_in[12];
    const void* vWd = d_in[13];
    const void* vWg = d_in[14];
    const void* vbg = d_in[15];
    const void* oW  = d_in[16];
    const void* ob  = d_in[17];

    // ws layout (33 MiB total — unchanged, proven):
    int*   flag = (int*)d_ws;
    float* fws  = (float*)d_ws;
    float* csum = fws + 64;
    float* gq   = csum + 32768;
    float* gk   = gq + 3 * M_ROWS;
    float* gv   = gk + 3 * M_ROWS;
    const size_t SZ = (size_t)M_ROWS * D_MODEL;
    u16* Ib = (u16*)((char*)d_ws + (1u << 20));
    u16* AO = Ib;                  // alias, disjoint in time
    u16* Qh = Ib + SZ;
    u16* Kh = Qh + SZ;
    u16* Vh = Kh + SZ;

    detect_kernel<<<1, 64, 0, stream>>>((const u32*)x, flag);
    scan_partial<<<128, 256, 0, stream>>>(x, csum, flag);
    scan_final<<<128, 256, 0, stream>>>(x, csum, Ib, flag);
    gates_kernel<<<M_ROWS, 64, 0, stream>>>(x, qWg, qbg, kWg, kbg, vWg, vbg,
                                            gq, gk, gv, flag);

    GemmArgs pa;
    pa.W[0][0] = qWp; pa.W[0][1] = qWi; pa.W[0][2] = qWd;
    pa.W[1][0] = kWp; pa.W[1][1] = kWi; pa.W[1][2] = kWd;
    pa.W[2][0] = vWp; pa.W[2][1] = vWi; pa.W[2][2] = vWd;
    pa.G[0] = gq; pa.G[1] = gk; pa.G[2] = gv;
    pa.C[0] = Qh; pa.C[1] = Kh; pa.C[2] = Vh;
    mfma_gemm<0><<<dim3(8, 32, 3), 256, 0, stream>>>(
        x, Ib, nullptr, pa, nullptr, nullptr, flag);

    attn_mfma<<<B_SZ * N_HEADS * (T_SEQ / 64), 256, 0, stream>>>(Qh, Kh, Vh, AO);

    GemmArgs oa = {};
    oa.W[0][0] = oW;
    mfma_gemm<1><<<dim3(8, 32, 1), 256, 0, stream>>>(
        nullptr, nullptr, AO, oa, ob, d_out, flag);
}

// Round 9
// 1096.104 us; speedup vs baseline: 1.0546x; 1.0546x over previous
//
#include <hip/hip_runtime.h>

// ---------------------------------------------------------------------------
// PIDMultiHeadAttention — Round 9.
// R8 (LDS-free) showed FETCH 400MB: without LDS each weight row is fetched
// 64x and the working set blows per-XCD L2 -> every frag load misses. LDS is
// mandatory. R6's DMA failed only because DOUBLE-buffering forces a vmcnt
// drain of next-buffer DMA before current-buffer reads. This round is the
// m97 structure verbatim: SINGLE-buffer global_load_lds staging,
//   stage(DMA) -> barrier(drain) -> ds_read frags + MFMA -> barrier
// with overlap from 3 resident blocks/CU (launch_bounds(256,3)), not
// intra-block pipelining. DMA lane map = fragment layout (R6-verified).
// seg2/fp32 paths stage via lane writes between the same barriers.
// ---------------------------------------------------------------------------

#define D_MODEL 1024
#define T_SEQ   2048
#define B_SZ    2
#define M_ROWS  (B_SZ * T_SEQ)   // 4096
#define N_HEADS 16
#define D_HEAD  64

typedef unsigned short u16;
typedef unsigned int   u32;

typedef short  short8  __attribute__((ext_vector_type(8)));
typedef float  float4v __attribute__((ext_vector_type(4)));

__device__ __forceinline__ float bf2f(u16 u) {
    union { u32 i; float f; } c; c.i = ((u32)u) << 16; return c.f;
}
__device__ __forceinline__ u16 f2bf(float f) {
    union { float f; u32 i; } c; c.f = f;
    u32 i = c.i;
    i += 0x7FFFu + ((i >> 16) & 1u);   // RNE
    return (u16)(i >> 16);
}
__device__ __forceinline__ float ldin(const void* p, int i, int fl) {
    return fl ? ((const float*)p)[i] : bf2f(((const u16*)p)[i]);
}

// async global->LDS, 16B per lane, dst = wave-uniform base + lane*16
__device__ __forceinline__ void gl_lds16(const u16* g, u16* s) {
    __builtin_amdgcn_global_load_lds(
        (const __attribute__((address_space(1))) u32*)g,
        (__attribute__((address_space(3))) u32*)s,
        16, 0, 0);
}

// ---------------------------------------------------------------------------
// 0) wire-dtype detection (unchanged — passing since round 2)
// ---------------------------------------------------------------------------
__global__ void detect_kernel(const u32* __restrict__ x, int* __restrict__ flag)
{
    if (threadIdx.x == 0 && blockIdx.x == 0) {
        int good = 0;
        for (int i = 0; i < 256; ++i) {
            union { u32 u; float f; } c; c.u = x[i];
            float a = fabsf(c.f);
            if (c.f == c.f && a > 1e-8f && a < 1e4f) ++good;
        }
        *flag = (good >= 192) ? 1 : 0;
    }
}

// ---------------------------------------------------------------------------
// 1) cumulative-mean scan (unchanged)
// ---------------------------------------------------------------------------
__global__ __launch_bounds__(256) void scan_partial(
    const void* __restrict__ x, float* __restrict__ csum,
    const int* __restrict__ flagp)
{
    int fl = *flagp;
    int tid = blockIdx.x * 256 + threadIdx.x;   // 32768 = B * 16 * D
    int b = tid >> 14;
    int c = (tid >> 10) & 15;
    int d = tid & 1023;
    int base = (b * T_SEQ + c * 128) * D_MODEL + d;
    float s = 0.f;
#pragma unroll 8
    for (int t = 0; t < 128; ++t) s += ldin(x, base + t * D_MODEL, fl);
    csum[tid] = s;
}

__global__ __launch_bounds__(256) void scan_final(
    const void* __restrict__ x, const float* __restrict__ csum,
    u16* __restrict__ integ, const int* __restrict__ flagp)
{
    int fl = *flagp;
    int tid = blockIdx.x * 256 + threadIdx.x;
    int b = tid >> 14;
    int c = (tid >> 10) & 15;
    int d = tid & 1023;
    float pre = 0.f;
    int cbase = (b << 14) | d;
    for (int cc = 0; cc < c; ++cc) pre += csum[cbase + (cc << 10)];
    int base = (b * T_SEQ + c * 128) * D_MODEL + d;
    float run = pre;
    int t0 = c * 128;
    for (int t = 0; t < 128; ++t) {
        run += ldin(x, base + t * D_MODEL, fl);
        integ[base + t * D_MODEL] = f2bf(run / (float)(t0 + t + 1));
    }
}

// ---------------------------------------------------------------------------
// 2) gate softmax (unchanged)
// ---------------------------------------------------------------------------
__global__ __launch_bounds__(64) void gates_kernel(
    const void* __restrict__ x,
    const void* __restrict__ qWg, const void* __restrict__ qbg,
    const void* __restrict__ kWg, const void* __restrict__ kbg,
    const void* __restrict__ vWg, const void* __restrict__ vbg,
    float* __restrict__ gq, float* __restrict__ gk, float* __restrict__ gv,
    const int* __restrict__ flagp)
{
    int fl = *flagp;
    int row = blockIdx.x;
    int l = threadIdx.x;
    int xb = row * D_MODEL;
    float p[9];
#pragma unroll
    for (int j = 0; j < 9; ++j) p[j] = 0.f;
#pragma unroll 4
    for (int i = 0; i < 16; ++i) {
        int d = l + 64 * i;
        float xv = ldin(x, xb + d, fl);
        p[0] += xv * ldin(qWg, d, fl);
        p[1] += xv * ldin(qWg, 1024 + d, fl);
        p[2] += xv * ldin(qWg, 2048 + d, fl);
        p[3] += xv * ldin(kWg, d, fl);
        p[4] += xv * ldin(kWg, 1024 + d, fl);
        p[5] += xv * ldin(kWg, 2048 + d, fl);
        p[6] += xv * ldin(vWg, d, fl);
        p[7] += xv * ldin(vWg, 1024 + d, fl);
        p[8] += xv * ldin(vWg, 2048 + d, fl);
    }
#pragma unroll
    for (int off = 32; off > 0; off >>= 1) {
#pragma unroll
        for (int j = 0; j < 9; ++j) p[j] += __shfl_down(p[j], off);
    }
    if (l == 0) {
        const void* bgs[3] = { qbg, kbg, vbg };
        float* outs[3] = { gq, gk, gv };
#pragma unroll
        for (int pr = 0; pr < 3; ++pr) {
            float a0 = p[pr * 3 + 0] + ldin(bgs[pr], 0, fl);
            float a1 = p[pr * 3 + 1] + ldin(bgs[pr], 1, fl);
            float a2 = p[pr * 3 + 2] + ldin(bgs[pr], 2, fl);
            float mx = fmaxf(a0, fmaxf(a1, a2));
            float e0 = __expf(a0 - mx), e1 = __expf(a1 - mx), e2 = __expf(a2 - mx);
            float inv = 1.f / (e0 + e1 + e2);
            outs[pr][row * 3 + 0] = e0 * inv;
            outs[pr][row * 3 + 1] = e1 * inv;
            outs[pr][row * 3 + 2] = e2 * inv;
        }
    }
}

// ---------------------------------------------------------------------------
// 3) MFMA GEMM, single-buffer global_load_lds staging (m97 structure).
//    Tile MT x 128 x 32. MODE 0: PID proj (K=3072 seg-major, g-fold at seg
//    boundaries). MODE 1: out proj (K=1024, +bias).
//    LDS groups of 1KiB: group g holds rows 16g..16g+15; lane slot l =
//    (row l&15, k-chunk l>>4) x 16B — matches DMA contract AND frag reads.
// ---------------------------------------------------------------------------
struct GemmArgs {
    const void* W[3][3];
    const float* G[3];
    u16* C[3];
};

template<int MODE, int MT>
__global__ __launch_bounds__(256, 3) void mfma_gemm(
    const void* __restrict__ X, const u16* __restrict__ Ib,
    const u16* __restrict__ Abf, GemmArgs args,
    const void* __restrict__ bias, void* __restrict__ outp,
    const int* __restrict__ flagp, int Ktot)
{
    constexpr int NAG  = MT / 16;              // A groups
    constexpr int NGR  = NAG + 8;              // total groups (B = 8)
    constexpr int NGPW = NGR / 4;              // groups per wave
    constexpr int ASZ  = MT * 32;              // A u16 per buffer
    constexpr int NS   = (MT == 128) ? 4 : 2;  // wave N-subtiles

    int fl = *flagp;
    __shared__ __align__(16) u16 As[ASZ];
    __shared__ __align__(16) u16 Bs[4096];

    int tid = threadIdx.x;
    int l = tid & 63, w = tid >> 6;
    int wm = (MT == 128) ? (w >> 1) : 0;
    int wn = (MT == 128) ? (w & 1) : w;
    int m0 = blockIdx.y * MT, n0 = blockIdx.x * 128;
    int z = blockIdx.z;
    int lane15 = l & 15, quad = l >> 4;
    int l15 = l & 15, kc = (l >> 4) * 8;       // staging lane map

    const void* W0; const void* W1; const void* W2;
    const float* G = nullptr;
    u16* Chead = nullptr;
    if (MODE == 0) {
        W0 = args.W[z][0]; W1 = args.W[z][1]; W2 = args.W[z][2];
        G = args.G[z]; Chead = args.C[z];
    } else {
        W0 = args.W[0][0]; W1 = W0; W2 = W0;
    }

    // lane staging fallback: 8 wire elems -> bf16 -> this lane's 16B slot
    auto stage_v8 = [&](const void* src, int idx, u16* dstg) {
        short8 pk;
        if (fl) {
            float4 t0 = *(const float4*)((const float*)src + idx);
            float4 t1 = *(const float4*)((const float*)src + idx + 4);
            pk[0] = (short)f2bf(t0.x); pk[1] = (short)f2bf(t0.y);
            pk[2] = (short)f2bf(t0.z); pk[3] = (short)f2bf(t0.w);
            pk[4] = (short)f2bf(t1.x); pk[5] = (short)f2bf(t1.y);
            pk[6] = (short)f2bf(t1.z); pk[7] = (short)f2bf(t1.w);
        } else {
            ushort4 a = *(const ushort4*)((const u16*)src + idx);
            ushort4 b = *(const ushort4*)((const u16*)src + idx + 4);
            pk[0] = (short)a.x; pk[1] = (short)a.y; pk[2] = (short)a.z; pk[3] = (short)a.w;
            pk[4] = (short)b.x; pk[5] = (short)b.y; pk[6] = (short)b.z; pk[7] = (short)b.w;
        }
        *(short8*)(dstg + l * 8) = pk;
    };

    auto stage = [&](int k0) {
        int seg = (MODE == 0) ? (k0 >> 10) : 0;
        int ksrc = k0 & 1023;
#pragma unroll
        for (int i = 0; i < NGPW; ++i) {
            int gid = w * NGPW + i;
            if (gid < NAG) {
                int g = gid;
                int gm = m0 + g * 16 + l15;
                int idx = gm * 1024 + ksrc + kc;
                u16* dst = As + g * 512;
                if (MODE == 1) {
                    gl_lds16(Abf + idx, dst);
                } else if (seg == 1) {
                    gl_lds16(Ib + idx, dst);
                } else if (seg == 0) {
                    if (fl) stage_v8(X, idx, dst);
                    else    gl_lds16((const u16*)X + idx, dst);
                } else {
                    // derivative: x[t] - x[t-1], zero at t==0 (lane path)
                    short8 pk;
                    if ((gm & (T_SEQ - 1)) == 0) {
#pragma unroll
                        for (int j = 0; j < 8; ++j) pk[j] = 0;
                    } else if (fl) {
                        const float* xp = (const float*)X;
                        float4 c0 = *(const float4*)(xp + idx);
                        float4 c1 = *(const float4*)(xp + idx + 4);
                        float4 p0 = *(const float4*)(xp + idx - 1024);
                        float4 p1 = *(const float4*)(xp + idx - 1020);
                        pk[0] = (short)f2bf(c0.x - p0.x); pk[1] = (short)f2bf(c0.y - p0.y);
                        pk[2] = (short)f2bf(c0.z - p0.z); pk[3] = (short)f2bf(c0.w - p0.w);
                        pk[4] = (short)f2bf(c1.x - p1.x); pk[5] = (short)f2bf(c1.y - p1.y);
                        pk[6] = (short)f2bf(c1.z - p1.z); pk[7] = (short)f2bf(c1.w - p1.w);
                    } else {
                        const u16* xp = (const u16*)X;
                        ushort4 c0 = *(const ushort4*)(xp + idx);
                        ushort4 c1 = *(const ushort4*)(xp + idx + 4);
                        ushort4 p0 = *(const ushort4*)(xp + idx - 1024);
                        ushort4 p1 = *(const ushort4*)(xp + idx - 1020);
                        pk[0] = (short)f2bf(bf2f(c0.x) - bf2f(p0.x));
                        pk[1] = (short)f2bf(bf2f(c0.y) - bf2f(p0.y));
                        pk[2] = (short)f2bf(bf2f(c0.z) - bf2f(p0.z));
                        pk[3] = (short)f2bf(bf2f(c0.w) - bf2f(p0.w));
                        pk[4] = (short)f2bf(bf2f(c1.x) - bf2f(p1.x));
                        pk[5] = (short)f2bf(bf2f(c1.y) - bf2f(p1.y));
                        pk[6] = (short)f2bf(bf2f(c1.z) - bf2f(p1.z));
                        pk[7] = (short)f2bf(bf2f(c1.w) - bf2f(p1.w));
                    }
                    *(short8*)(dst + l * 8) = pk;
                }
            } else {
                int g = gid - NAG;
                int gn = n0 + g * 16 + l15;
                int idx = gn * 1024 + ksrc + kc;
                const void* Wse = (MODE == 0)
                    ? (seg == 0 ? W0 : (seg == 1 ? W1 : W2)) : W0;
                u16* dst = Bs + g * 512;
                if (fl) stage_v8(Wse, idx, dst);
                else    gl_lds16((const u16*)Wse + idx, dst);
            }
        }
    };

    float4v accs[4][NS], acct[4][NS];
#pragma unroll
    for (int i = 0; i < 4; ++i)
#pragma unroll
        for (int j = 0; j < NS; ++j)
#pragma unroll
            for (int r = 0; r < 4; ++r) { accs[i][j][r] = 0.f; acct[i][j][r] = 0.f; }

    int nIt = Ktot >> 5;
    for (int it = 0; it < nIt; ++it) {
        stage(it << 5);
        __syncthreads();               // drains DMA vmcnt + lane lgkm -> LDS ready

        short8 af[4], bfr[NS];
#pragma unroll
        for (int ms = 0; ms < 4; ++ms)
            af[ms] = *(const short8*)&As[(wm * 4 + ms) * 512 + quad * 128 + lane15 * 8];
#pragma unroll
        for (int ns = 0; ns < NS; ++ns)
            bfr[ns] = *(const short8*)&Bs[(wn * NS + ns) * 512 + quad * 128 + lane15 * 8];
#pragma unroll
        for (int ms = 0; ms < 4; ++ms)
#pragma unroll
            for (int ns = 0; ns < NS; ++ns)
                accs[ms][ns] = __builtin_amdgcn_mfma_f32_16x16x32_bf16(
                    af[ms], bfr[ns], accs[ms][ns], 0, 0, 0);

        // fold seg-partial into total with per-row g at segment boundaries
        if (MODE == 0 && (it & 31) == 31) {
            int seg = it >> 5;
#pragma unroll
            for (int ms = 0; ms < 4; ++ms) {
#pragma unroll
                for (int r = 0; r < 4; ++r) {
                    int m = m0 + wm * 64 + ms * 16 + quad * 4 + r;
                    float gv = G[m * 3 + seg];
#pragma unroll
                    for (int ns = 0; ns < NS; ++ns) {
                        acct[ms][ns][r] += gv * accs[ms][ns][r];
                        accs[ms][ns][r] = 0.f;
                    }
                }
            }
        }
        __syncthreads();               // protect LDS before next stage
    }

    // ---- epilogue (proven R6/R7) ----
#pragma unroll
    for (int ms = 0; ms < 4; ++ms) {
#pragma unroll
        for (int r = 0; r < 4; ++r) {
            int m = m0 + wm * 64 + ms * 16 + quad * 4 + r;
#pragma unroll
            for (int ns = 0; ns < NS; ++ns) {
                int n = n0 + (wn * NS + ns) * 16 + lane15;
                if (MODE == 0) {
                    float vv = acct[ms][ns][r];
                    int b = m >> 11, t = m & (T_SEQ - 1);
                    int h = n >> 6,  d = n & 63;
                    Chead[(((b << 4) + h) * T_SEQ + t) * 64 + d] = f2bf(vv);
                } else {
                    float vv = accs[ms][ns][r] + ldin(bias, n, fl);
                    if (fl) ((float*)outp)[m * 1024 + n] = vv;
                    else    ((u16*)outp)[m * 1024 + n] = f2bf(vv);
                }
            }
        }
    }
}

// ---------------------------------------------------------------------------
// 4) MFMA flash attention (unchanged — passing since round 3)
// ---------------------------------------------------------------------------
__global__ __launch_bounds__(256) void attn_mfma(
    const u16* __restrict__ Qh, const u16* __restrict__ Kh,
    const u16* __restrict__ Vh, u16* __restrict__ AO)
{
    int bx = blockIdx.x;          // 1024 = B*H*(T/64)
    int qt = bx & 31;
    int bh = bx >> 5;             // 0..31
    int h  = bh & 15;
    int b  = bh >> 4;
    int tid = threadIdx.x;
    int l   = tid & 63;
    int w   = tid >> 6;
    int lane15 = l & 15;
    int quad   = l >> 4;

    __shared__ __align__(16) u16 Ks[64 * 72];
    __shared__ __align__(16) u16 Vt[64 * 72];   // transposed: [d][t_local]
    __shared__ __align__(16) u16 Ps[4 * 16 * 72];

    const u16* Qb = Qh + bh * (T_SEQ * 64);
    const u16* Kb = Kh + bh * (T_SEQ * 64);
    const u16* Vb = Vh + bh * (T_SEQ * 64);

    int qrow = qt * 64 + w * 16 + lane15;
    short8 qf[2];
#pragma unroll
    for (int ks = 0; ks < 2; ++ks)
        qf[ks] = *(const short8*)&Qb[qrow * 64 + ks * 32 + quad * 8];

    float4v oacc[4];
#pragma unroll
    for (int ds = 0; ds < 4; ++ds)
#pragma unroll
        for (int r = 0; r < 4; ++r) oacc[ds][r] = 0.f;
    float mrun[4], lrun[4];
#pragma unroll
    for (int r = 0; r < 4; ++r) { mrun[r] = -1e30f; lrun[r] = 0.f; }

    int srow = tid >> 2;
    int sdc  = (tid & 3) * 16;

    for (int kt = 0; kt <= qt; ++kt) {
        {
            const u16* kp = &Kb[(kt * 64 + srow) * 64 + sdc];
            ushort4 a = *(const ushort4*)kp;
            ushort4 c = *(const ushort4*)(kp + 4);
            ushort4 d2 = *(const ushort4*)(kp + 8);
            ushort4 e = *(const ushort4*)(kp + 12);
            short8 p0, p1;
            p0[0]=a.x; p0[1]=a.y; p0[2]=a.z; p0[3]=a.w;
            p0[4]=c.x; p0[5]=c.y; p0[6]=c.z; p0[7]=c.w;
            p1[0]=d2.x; p1[1]=d2.y; p1[2]=d2.z; p1[3]=d2.w;
            p1[4]=e.x; p1[5]=e.y; p1[6]=e.z; p1[7]=e.w;
            *(short8*)&Ks[srow * 72 + sdc] = p0;
            *(short8*)&Ks[srow * 72 + sdc + 8] = p1;

            const u16* vp = &Vb[(kt * 64 + srow) * 64 + sdc];
            u16 vv[16];
            *(ushort4*)&vv[0]  = *(const ushort4*)vp;
            *(ushort4*)&vv[4]  = *(const ushort4*)(vp + 4);
            *(ushort4*)&vv[8]  = *(const ushort4*)(vp + 8);
            *(ushort4*)&vv[12] = *(const ushort4*)(vp + 12);
#pragma unroll
            for (int e2 = 0; e2 < 16; ++e2)
                Vt[(sdc + e2) * 72 + srow] = vv[e2];
        }
        __syncthreads();

        float4v sacc[4];
#pragma unroll
        for (int ns = 0; ns < 4; ++ns)
#pragma unroll
            for (int r = 0; r < 4; ++r) sacc[ns][r] = 0.f;
#pragma unroll
        for (int ks = 0; ks < 2; ++ks) {
#pragma unroll
            for (int ns = 0; ns < 4; ++ns) {
                short8 bfk = *(const short8*)&Ks[(ns * 16 + lane15) * 72 + ks * 32 + quad * 8];
                sacc[ns] = __builtin_amdgcn_mfma_f32_16x16x32_bf16(
                    qf[ks], bfk, sacc[ns], 0, 0, 0);
            }
        }

        int qg0 = qt * 64 + w * 16 + quad * 4;
#pragma unroll
        for (int ns = 0; ns < 4; ++ns) {
            int kg = kt * 64 + ns * 16 + lane15;
#pragma unroll
            for (int r = 0; r < 4; ++r) {
                float s = sacc[ns][r] * 0.125f;
                sacc[ns][r] = (kg > qg0 + r) ? -1e30f : s;
            }
        }
#pragma unroll
        for (int r = 0; r < 4; ++r) {
            float mx = fmaxf(fmaxf(sacc[0][r], sacc[1][r]),
                             fmaxf(sacc[2][r], sacc[3][r]));
#pragma unroll
            for (int m2 = 1; m2 < 16; m2 <<= 1)
                mx = fmaxf(mx, __shfl_xor(mx, m2, 64));
            float mnew = fmaxf(mrun[r], mx);
            float al = __expf(mrun[r] - mnew);
            float rs = 0.f;
#pragma unroll
            for (int ns = 0; ns < 4; ++ns) {
                float p = __expf(sacc[ns][r] - mnew);
                sacc[ns][r] = p;
                rs += p;
            }
#pragma unroll
            for (int m2 = 1; m2 < 16; m2 <<= 1)
                rs += __shfl_xor(rs, m2, 64);
            lrun[r] = lrun[r] * al + rs;
            mrun[r] = mnew;
#pragma unroll
            for (int ds = 0; ds < 4; ++ds) oacc[ds][r] *= al;
        }

        u16* Pw = &Ps[w * 16 * 72];
#pragma unroll
        for (int ns = 0; ns < 4; ++ns)
#pragma unroll
            for (int r = 0; r < 4; ++r)
                Pw[(quad * 4 + r) * 72 + ns * 16 + lane15] = f2bf(sacc[ns][r]);

#pragma unroll
        for (int ks = 0; ks < 2; ++ks) {
            short8 afp = *(const short8*)&Pw[lane15 * 72 + ks * 32 + quad * 8];
#pragma unroll
            for (int ds = 0; ds < 4; ++ds) {
                short8 bfv = *(const short8*)&Vt[(ds * 16 + lane15) * 72 + ks * 32 + quad * 8];
                oacc[ds] = __builtin_amdgcn_mfma_f32_16x16x32_bf16(
                    afp, bfv, oacc[ds], 0, 0, 0);
            }
        }
        __syncthreads();
    }

#pragma unroll
    for (int r = 0; r < 4; ++r) {
        float inv = 1.f / lrun[r];
        int t = qt * 64 + w * 16 + quad * 4 + r;
        int orow = (b * T_SEQ + t) * 1024 + h * 64;
#pragma unroll
        for (int ds = 0; ds < 4; ++ds)
            AO[orow + ds * 16 + lane15] = f2bf(oacc[ds][r] * inv);
    }
}

// ---------------------------------------------------------------------------
extern "C" void kernel_launch(void* const* d_in, const int* in_sizes, int n_in,
                              void* d_out, int out_size, void* d_ws, size_t ws_size,
                              hipStream_t stream)
{
    const void* x   = d_in[0];
    const void* qWp = d_in[1];
    const void* qWi = d_in[2];
    const void* qWd = d_in[3];
    const void* qWg = d_in[4];
    const void* qbg = d_in[5];
    const void* kWp = d_in[6];
    const void* kWi = d_in[7];
    const void* kWd = d_in[8];
    const void* kWg = d_in[9];
    const void* kbg = d_in[10];
    const void* vWp = d_in[11];
    const void* vWi = d_in[12];
    const void* vWd = d_in[13];
    const void* vWg = d_in[14];
    const void* vbg = d_in[15];
    const void* oW  = d_in[16];
    const void* ob  = d_in[17];

    // ws layout (33 MiB total — unchanged, proven):
    int*   flag = (int*)d_ws;
    float* fws  = (float*)d_ws;
    float* csum = fws + 64;
    float* gq   = csum + 32768;
    float* gk   = gq + 3 * M_ROWS;
    float* gv   = gk + 3 * M_ROWS;
    const size_t SZ = (size_t)M_ROWS * D_MODEL;
    u16* Ib = (u16*)((char*)d_ws + (1u << 20));
    u16* AO = Ib;                  // alias, disjoint in time
    u16* Qh = Ib + SZ;
    u16* Kh = Qh + SZ;
    u16* Vh = Kh + SZ;

    detect_kernel<<<1, 64, 0, stream>>>((const u32*)x, flag);
    scan_partial<<<128, 256, 0, stream>>>(x, csum, flag);
    scan_final<<<128, 256, 0, stream>>>(x, csum, Ib, flag);
    gates_kernel<<<M_ROWS, 64, 0, stream>>>(x, qWg, qbg, kWg, kbg, vWg, vbg,
                                            gq, gk, gv, flag);

    GemmArgs pa;
    pa.W[0][0] = qWp; pa.W[0][1] = qWi; pa.W[0][2] = qWd;
    pa.W[1][0] = kWp; pa.W[1][1] = kWi; pa.W[1][2] = kWd;
    pa.W[2][0] = vWp; pa.W[2][1] = vWi; pa.W[2][2] = vWd;
    pa.G[0] = gq; pa.G[1] = gk; pa.G[2] = gv;
    pa.C[0] = Qh; pa.C[1] = Kh; pa.C[2] = Vh;
    mfma_gemm<0, 128><<<dim3(8, 32, 3), 256, 0, stream>>>(
        x, Ib, nullptr, pa, nullptr, nullptr, flag, 3072);

    attn_mfma<<<B_SZ * N_HEADS * (T_SEQ / 64), 256, 0, stream>>>(Qh, Kh, Vh, AO);

    GemmArgs oa = {};
    oa.W[0][0] = oW;
    mfma_gemm<1, 64><<<dim3(8, 64, 1), 256, 0, stream>>>(
        nullptr, nullptr, AO, oa, ob, d_out, flag, 1024);
}